// Round 5
// baseline (110.421 us; speedup 1.0000x reference)
//
#include <hip/hip_runtime.h>
#include <hip/hip_bf16.h>

typedef __bf16 bf16;
typedef __attribute__((ext_vector_type(4))) __bf16 bf16x4;
typedef __attribute__((ext_vector_type(8))) __bf16 bf16x8;
typedef __attribute__((ext_vector_type(4))) float f32x4;

#define GLD_LDS16(g, l)                                              \
  __builtin_amdgcn_global_load_lds(                                  \
      (const __attribute__((address_space(1))) void*)(g),            \
      (__attribute__((address_space(3))) void*)(l), 16, 0, 0)

// ---------------- cast f32 -> bf16, vectorized ----------------
__global__ void cast_bf16_kernel(const float* __restrict__ in,
                                 bf16* __restrict__ out, int n4) {
  int i = blockIdx.x * blockDim.x + threadIdx.x;
  if (i >= n4) return;
  float4 v = reinterpret_cast<const float4*>(in)[i];
  bf16x4 o;
  o[0] = (bf16)v.x; o[1] = (bf16)v.y; o[2] = (bf16)v.z; o[3] = (bf16)v.w;
  reinterpret_cast<bf16x4*>(out)[i] = o;
}

// ------- transpose + cast W (K,N) -> Wt (N,K) bf16; [3][1024][1024] -------
__global__ void transpose_cast_kernel(const float* __restrict__ Wq,
                                      const float* __restrict__ Wk,
                                      const float* __restrict__ Wv,
                                      bf16* __restrict__ Wt) {
  __shared__ float tile[32][33];
  const int z = blockIdx.z;
  const float* W = (z == 0) ? Wq : ((z == 1) ? Wk : Wv);
  bf16* out = Wt + (size_t)z * 1024 * 1024;
  const int k0 = blockIdx.x * 32, n0 = blockIdx.y * 32;
  const int t = threadIdx.x;
  const int r = t >> 3, c = (t & 7) * 4;
  float4 v = *reinterpret_cast<const float4*>(&W[(size_t)(k0 + r) * 1024 + n0 + c]);
  tile[r][c + 0] = v.x; tile[r][c + 1] = v.y;
  tile[r][c + 2] = v.z; tile[r][c + 3] = v.w;
  __syncthreads();
  bf16x4 o;
  o[0] = (bf16)tile[c + 0][r]; o[1] = (bf16)tile[c + 1][r];
  o[2] = (bf16)tile[c + 2][r]; o[3] = (bf16)tile[c + 3][r];
  *reinterpret_cast<bf16x4*>(&out[(size_t)(n0 + r) * 1024 + k0 + c]) = o;
}

// --------- fused QKV GEMM: C[8192][3072] = x @ Wt^T + bias ----------------
// BM=256 BN=128 BK=64, 8 waves (4Mx2N, per-wave 64x64), 3-deep LDS pipeline,
// counted vmcnt(6), XOR-swizzle (row&7)<<4, ONE barrier per K-tile:
// stages issued first, reads+MFMA free-run (wave-level overlap).
__global__ __launch_bounds__(512, 2) void qkv_gemm_kernel(
    const bf16* __restrict__ xb, const bf16* __restrict__ Wt,
    const float* __restrict__ bq, const float* __restrict__ bk,
    const float* __restrict__ bv, bf16* __restrict__ QKV) {
  __shared__ bf16 ldsA[3][256 * 64];  // 96 KB (3 x 32 KB)
  __shared__ bf16 ldsB[3][128 * 64];  // 48 KB (3 x 16 KB)

  const int n0g = blockIdx.x * 128;     // global col tile (0..2944)
  const int m0 = blockIdx.y * 256;      // global row tile
  const int z = n0g >> 10;              // which of q/k/v
  const float* bias = (z == 0) ? bq : ((z == 1) ? bk : bv);
  const int nloc = n0g & 1023;

  const int t = threadIdx.x;
  const int lane = t & 63, wid = t >> 6;
  const int wr = wid >> 1, wc = wid & 1;     // 4M x 2N waves
  const int l15 = lane & 15, kg = lane >> 4;

  // staging geometry: chunk = 64 rows x 64 cols (8 KB), 512 thr x 16 B
  const int trow = t >> 3;                              // 0..63
  const int cdst = (t & 7) * 8;                         // LDS col (elems)
  const int csrc = (((t & 7) * 16) ^ ((trow & 7) << 4)) >> 1;  // swizzled src

  bf16* const A0 = &ldsA[0][0]; bf16* const A1 = &ldsA[1][0]; bf16* const A2 = &ldsA[2][0];
  bf16* const B0 = &ldsB[0][0]; bf16* const B1 = &ldsB[1][0]; bf16* const B2 = &ldsB[2][0];

  auto stageA = [&](int c, int kt, bf16* Ab) {
    GLD_LDS16(xb + (size_t)(m0 + c * 64 + trow) * 1024 + kt + csrc,
              Ab + (c * 64 + trow) * 64 + cdst);
  };
  auto stageB = [&](int c, int kt, bf16* Bb) {
    GLD_LDS16(Wt + (size_t)(n0g + c * 64 + trow) * 1024 + kt + csrc,
              Bb + (c * 64 + trow) * 64 + cdst);
  };
  // swizzled fragment reads (row&7 == l15&7 since offsets are x16)
  auto readA = [&](const bf16* Ab, int mi, int ks) {
    const int row = wr * 64 + mi * 16 + l15;
    const int colb = (ks * 64 + kg * 16) ^ ((l15 & 7) << 4);
    return *reinterpret_cast<const bf16x8*>(Ab + row * 64 + (colb >> 1));
  };
  auto readB = [&](const bf16* Bb, int ni, int ks) {
    const int row = wc * 64 + ni * 16 + l15;
    const int colb = (ks * 64 + kg * 16) ^ ((l15 & 7) << 4);
    return *reinterpret_cast<const bf16x8*>(Bb + row * 64 + (colb >> 1));
  };

  f32x4 acc[4][4];
#pragma unroll
  for (int i = 0; i < 4; ++i)
#pragma unroll
    for (int j = 0; j < 4; ++j) { f32x4 zz = {0.f, 0.f, 0.f, 0.f}; acc[i][j] = zz; }

  // prologue: stage tile 0 -> buf0, tile 1 -> buf1 (12 loads outstanding)
#pragma unroll
  for (int c = 0; c < 4; ++c) stageA(c, 0, A0);
#pragma unroll
  for (int c = 0; c < 2; ++c) stageB(c, 0, B0);
#pragma unroll
  for (int c = 0; c < 4; ++c) stageA(c, 64, A1);
#pragma unroll
  for (int c = 0; c < 2; ++c) stageB(c, 64, B1);

  bf16 *Ar = A0, *An = A1, *Aw = A2;
  bf16 *Br = B0, *Bn = B1, *Bw = B2;

  for (int tt = 0; tt < 16; ++tt) {
    // boundary: retire tile tt's 6 loads, keep tile tt+1's 6 in flight.
    // This barrier also WAR-protects Aw/Bw (last read during tile tt-1).
    if (tt < 15) asm volatile("s_waitcnt vmcnt(6)" ::: "memory");
    else         asm volatile("s_waitcnt vmcnt(0)" ::: "memory");
    __builtin_amdgcn_s_barrier();

    // issue next-next tile's stages FIRST (max time in flight)
    const int ktgt = (tt + 2) * 64;
    if (tt < 14) {
      stageA(0, ktgt, Aw); stageA(1, ktgt, Aw);
      stageA(2, ktgt, Aw); stageA(3, ktgt, Aw);
      stageB(0, ktgt, Bw); stageB(1, ktgt, Bw);
    }

    // fragment reads (compiler interleaves lgkmcnt with MFMA below)
    bf16x8 af[4][2], bfr[4][2];
#pragma unroll
    for (int mi = 0; mi < 4; ++mi)
#pragma unroll
      for (int ks = 0; ks < 2; ++ks) af[mi][ks] = readA(Ar, mi, ks);
#pragma unroll
    for (int ni = 0; ni < 4; ++ni)
#pragma unroll
      for (int ks = 0; ks < 2; ++ks) bfr[ni][ks] = readB(Br, ni, ks);

    __builtin_amdgcn_s_setprio(1);
#pragma unroll
    for (int mi = 0; mi < 4; ++mi)
#pragma unroll
      for (int ni = 0; ni < 4; ++ni) {
        acc[mi][ni] = __builtin_amdgcn_mfma_f32_16x16x32_bf16(af[mi][0], bfr[ni][0], acc[mi][ni], 0, 0, 0);
        acc[mi][ni] = __builtin_amdgcn_mfma_f32_16x16x32_bf16(af[mi][1], bfr[ni][1], acc[mi][ni], 0, 0, 0);
      }
    __builtin_amdgcn_s_setprio(0);

    bf16* tA = Ar; Ar = An; An = Aw; Aw = tA;
    bf16* tB = Br; Br = Bn; Bn = Bw; Bw = tB;
  }

  // epilogue: C/D layout col = lane&15, row = (lane>>4)*4 + reg  [m89/m91]
  const int rowb = kg * 4;
#pragma unroll
  for (int ni = 0; ni < 4; ++ni) {
    const int cl = wc * 64 + ni * 16 + l15;
    const float bv_ = bias[nloc + cl];
#pragma unroll
    for (int mi = 0; mi < 4; ++mi) {
      const int row = m0 + wr * 64 + mi * 16 + rowb;
#pragma unroll
      for (int j = 0; j < 4; ++j)
        QKV[(size_t)(row + j) * 3072 + n0g + cl] = (bf16)(acc[mi][ni][j] + bv_);
    }
  }
}

// ------- local attention, window +-2; QKV fused rows [p][3072] ------------
__global__ void local_attn_kernel(const bf16* __restrict__ QKV,
                                  float* __restrict__ out) {
  const int t = threadIdx.x;
  const int lane = t & 63, wid = t >> 6;
  const int p = blockIdx.x * 4 + wid;  // b*2048 + s
  const int s = p & 2047;
  const size_t hoff = (size_t)lane * 16;

  float qf[16];
  {
    const bf16* qp = QKV + (size_t)p * 3072 + hoff;
    bf16x8 q0 = *reinterpret_cast<const bf16x8*>(qp);
    bf16x8 q1 = *reinterpret_cast<const bf16x8*>(qp + 8);
#pragma unroll
    for (int j = 0; j < 8; ++j) { qf[j] = (float)q0[j]; qf[8 + j] = (float)q1[j]; }
  }

  float sc[5];
#pragma unroll
  for (int w = 0; w < 5; ++w) {
    const int sp = s + w - 2;  // wave-uniform
    if (sp < 0 || sp >= 2048) { sc[w] = -__builtin_inff(); continue; }
    const bf16* kp = QKV + (size_t)(p + w - 2) * 3072 + 1024 + hoff;
    bf16x8 k0 = *reinterpret_cast<const bf16x8*>(kp);
    bf16x8 k1 = *reinterpret_cast<const bf16x8*>(kp + 8);
    float d = 0.f;
#pragma unroll
    for (int j = 0; j < 8; ++j) d += qf[j] * (float)k0[j] + qf[8 + j] * (float)k1[j];
#pragma unroll
    for (int off = 32; off >= 1; off >>= 1) d += __shfl_xor(d, off, 64);
    sc[w] = d * (1.0f / 32.0f);  // /sqrt(1024)
  }

  float m = -__builtin_inff();
#pragma unroll
  for (int w = 0; w < 5; ++w) m = fmaxf(m, sc[w]);
  float e[5], sum = 0.f;
#pragma unroll
  for (int w = 0; w < 5; ++w) { e[w] = __expf(sc[w] - m); sum += e[w]; }
  const float inv = 1.0f / sum;

  float of[16];
#pragma unroll
  for (int j = 0; j < 16; ++j) of[j] = 0.f;
#pragma unroll
  for (int w = 0; w < 5; ++w) {
    const int sp = s + w - 2;
    if (sp < 0 || sp >= 2048) continue;
    const float pw = e[w] * inv;
    const bf16* vp = QKV + (size_t)(p + w - 2) * 3072 + 2048 + hoff;
    bf16x8 v0 = *reinterpret_cast<const bf16x8*>(vp);
    bf16x8 v1 = *reinterpret_cast<const bf16x8*>(vp + 8);
#pragma unroll
    for (int j = 0; j < 8; ++j) { of[j] += pw * (float)v0[j]; of[8 + j] += pw * (float)v1[j]; }
  }

  float* op = out + (size_t)p * 1024 + hoff;
#pragma unroll
  for (int j4 = 0; j4 < 4; ++j4) {
    f32x4 o = {of[4 * j4 + 0], of[4 * j4 + 1], of[4 * j4 + 2], of[4 * j4 + 3]};
    *reinterpret_cast<f32x4*>(op + 4 * j4) = o;
  }
}

extern "C" void kernel_launch(void* const* d_in, const int* in_sizes, int n_in,
                              void* d_out, int out_size, void* d_ws,
                              size_t ws_size, hipStream_t stream) {
  const float* x  = (const float*)d_in[0];
  const float* Wq = (const float*)d_in[1];
  const float* bq = (const float*)d_in[2];
  const float* Wk = (const float*)d_in[3];
  const float* bk = (const float*)d_in[4];
  const float* Wv = (const float*)d_in[5];
  const float* bv = (const float*)d_in[6];

  char* ws = (char*)d_ws;
  bf16* xb  = (bf16*)ws;                       // 16 MB: x as bf16
  bf16* Wt  = (bf16*)(ws + (size_t)16777216);  // 6 MB: [3072][1024] W^T bf16
  bf16* QKV = (bf16*)(ws + (size_t)23068672);  // 48 MB: fused [8192][3072]
  float* outf = (float*)d_out;

  cast_bf16_kernel<<<8192, 256, 0, stream>>>(x, xb, 8192 * 1024 / 4);
  transpose_cast_kernel<<<dim3(32, 32, 3), 256, 0, stream>>>(Wq, Wk, Wv, Wt);
  qkv_gemm_kernel<<<dim3(24, 32), 512, 0, stream>>>(xb, Wt, bq, bk, bv, QKV);
  local_attn_kernel<<<2048, 256, 0, stream>>>(QKV, outf);
}

// Round 7
// 99.058 us; speedup vs baseline: 1.1147x; 1.1147x over previous
//
#include <hip/hip_runtime.h>
#include <hip/hip_bf16.h>

typedef __bf16 bf16;
typedef __attribute__((ext_vector_type(4))) __bf16 bf16x4;
typedef __attribute__((ext_vector_type(8))) __bf16 bf16x8;
typedef __attribute__((ext_vector_type(4))) float f32x4;

#define GLD_LDS16(g, l)                                              \
  __builtin_amdgcn_global_load_lds(                                  \
      (const __attribute__((address_space(1))) void*)(g),            \
      (__attribute__((address_space(3))) void*)(l), 16, 0, 0)

// ---------------- cast f32 -> bf16, vectorized ----------------
__global__ void cast_bf16_kernel(const float* __restrict__ in,
                                 bf16* __restrict__ out, int n4) {
  int i = blockIdx.x * blockDim.x + threadIdx.x;
  if (i >= n4) return;
  float4 v = reinterpret_cast<const float4*>(in)[i];
  bf16x4 o;
  o[0] = (bf16)v.x; o[1] = (bf16)v.y; o[2] = (bf16)v.z; o[3] = (bf16)v.w;
  reinterpret_cast<bf16x4*>(out)[i] = o;
}

// ------- transpose + cast W (K,N) -> Wt (N,K) bf16; [3][1024][1024] -------
__global__ void transpose_cast_kernel(const float* __restrict__ Wq,
                                      const float* __restrict__ Wk,
                                      const float* __restrict__ Wv,
                                      bf16* __restrict__ Wt) {
  __shared__ float tile[32][33];
  const int z = blockIdx.z;
  const float* W = (z == 0) ? Wq : ((z == 1) ? Wk : Wv);
  bf16* out = Wt + (size_t)z * 1024 * 1024;
  const int k0 = blockIdx.x * 32, n0 = blockIdx.y * 32;
  const int t = threadIdx.x;
  const int r = t >> 3, c = (t & 7) * 4;
  float4 v = *reinterpret_cast<const float4*>(&W[(size_t)(k0 + r) * 1024 + n0 + c]);
  tile[r][c + 0] = v.x; tile[r][c + 1] = v.y;
  tile[r][c + 2] = v.z; tile[r][c + 3] = v.w;
  __syncthreads();
  bf16x4 o;
  o[0] = (bf16)tile[c + 0][r]; o[1] = (bf16)tile[c + 1][r];
  o[2] = (bf16)tile[c + 2][r]; o[3] = (bf16)tile[c + 3][r];
  *reinterpret_cast<bf16x4*>(&out[(size_t)(n0 + r) * 1024 + k0 + c]) = o;
}

// --------- fused QKV GEMM: C[8192][3072] = x @ Wt^T + bias ----------------
// BM=256 BN=128 BK=64, 8 waves (4Mx2N, 64x64/wave), 3-deep pipeline with
// COMPILE-TIME-CONSTANT buffer indices (unrolled mod-3 + peeled tail) so the
// backend can alias-disambiguate ds_read vs in-flight global_load_lds and the
// counted vmcnt(6) actually keeps loads in flight across barriers.
__global__ __launch_bounds__(512, 2) void qkv_gemm_kernel(
    const bf16* __restrict__ xb, const bf16* __restrict__ Wt,
    const float* __restrict__ bq, const float* __restrict__ bk,
    const float* __restrict__ bv, bf16* __restrict__ QKV) {
  __shared__ bf16 ldsA[3][256 * 64];  // 96 KB
  __shared__ bf16 ldsB[3][128 * 64];  // 48 KB

  const int n0g = blockIdx.x * 128;
  const int m0 = blockIdx.y * 256;
  const int z = n0g >> 10;
  const float* bias = (z == 0) ? bq : ((z == 1) ? bk : bv);
  const int nloc = n0g & 1023;

  const int t = threadIdx.x;
  const int lane = t & 63, wid = t >> 6;
  const int wr = wid >> 1, wc = wid & 1;
  const int l15 = lane & 15, kg = lane >> 4;

  // staging: chunk = 64 rows x 64 cols (8 KB), 512 thr x 16 B
  const int trow = t >> 3;
  const int cdst = (t & 7) * 8;
  const int csrc = (((t & 7) * 16) ^ ((trow & 7) << 4)) >> 1;  // pre-swizzled src

  auto stageA = [&](int c, int kt, bf16* Ab) {
    GLD_LDS16(xb + (size_t)(m0 + c * 64 + trow) * 1024 + kt + csrc,
              Ab + (c * 64 + trow) * 64 + cdst);
  };
  auto stageB = [&](int c, int kt, bf16* Bb) {
    GLD_LDS16(Wt + (size_t)(n0g + c * 64 + trow) * 1024 + kt + csrc,
              Bb + (c * 64 + trow) * 64 + cdst);
  };
  auto readA = [&](const bf16* Ab, int mi, int ks) {
    const int row = wr * 64 + mi * 16 + l15;
    const int colb = (ks * 64 + kg * 16) ^ ((l15 & 7) << 4);
    return *reinterpret_cast<const bf16x8*>(Ab + row * 64 + (colb >> 1));
  };
  auto readB = [&](const bf16* Bb, int ni, int ks) {
    const int row = wc * 64 + ni * 16 + l15;
    const int colb = (ks * 64 + kg * 16) ^ ((l15 & 7) << 4);
    return *reinterpret_cast<const bf16x8*>(Bb + row * 64 + (colb >> 1));
  };

  f32x4 acc[4][4];
#pragma unroll
  for (int i = 0; i < 4; ++i)
#pragma unroll
    for (int j = 0; j < 4; ++j) { f32x4 zz = {0.f, 0.f, 0.f, 0.f}; acc[i][j] = zz; }

  // prologue: tile 0 -> buf0, tile 1 -> buf1 (12 loads in flight)
#pragma unroll
  for (int c = 0; c < 4; ++c) stageA(c, 0, &ldsA[0][0]);
#pragma unroll
  for (int c = 0; c < 2; ++c) stageB(c, 0, &ldsB[0][0]);
#pragma unroll
  for (int c = 0; c < 4; ++c) stageA(c, 64, &ldsA[1][0]);
#pragma unroll
  for (int c = 0; c < 2; ++c) stageB(c, 64, &ldsB[1][0]);

// One K-tile. RB/WB are LITERAL buffer indices. Order: boundary wait+barrier,
// fragment reads (pinned first), stage issue, MFMA cluster.
#define KTILE(RB, WB, kt, DO_STAGE, LAST)                                      \
  {                                                                            \
    if (LAST) { asm volatile("s_waitcnt vmcnt(0)" ::: "memory"); }             \
    else      { asm volatile("s_waitcnt vmcnt(6)" ::: "memory"); }             \
    __builtin_amdgcn_s_barrier();                                              \
    bf16x8 af[4][2], bfr[4][2];                                                \
    _Pragma("unroll")                                                          \
    for (int mi = 0; mi < 4; ++mi)                                             \
      _Pragma("unroll")                                                        \
      for (int ks = 0; ks < 2; ++ks) af[mi][ks] = readA(&ldsA[RB][0], mi, ks); \
    _Pragma("unroll")                                                          \
    for (int ni = 0; ni < 4; ++ni)                                             \
      _Pragma("unroll")                                                        \
      for (int ks = 0; ks < 2; ++ks) bfr[ni][ks] = readB(&ldsB[RB][0], ni, ks);\
    __builtin_amdgcn_sched_barrier(0);                                         \
    if (DO_STAGE) {                                                            \
      stageA(0, (kt) + 128, &ldsA[WB][0]);                                     \
      stageA(1, (kt) + 128, &ldsA[WB][0]);                                     \
      stageA(2, (kt) + 128, &ldsA[WB][0]);                                     \
      stageA(3, (kt) + 128, &ldsA[WB][0]);                                     \
      stageB(0, (kt) + 128, &ldsB[WB][0]);                                     \
      stageB(1, (kt) + 128, &ldsB[WB][0]);                                     \
    }                                                                          \
    __builtin_amdgcn_s_setprio(1);                                             \
    _Pragma("unroll")                                                          \
    for (int mi = 0; mi < 4; ++mi)                                             \
      _Pragma("unroll")                                                        \
      for (int ni = 0; ni < 4; ++ni) {                                         \
        acc[mi][ni] = __builtin_amdgcn_mfma_f32_16x16x32_bf16(                 \
            af[mi][0], bfr[ni][0], acc[mi][ni], 0, 0, 0);                      \
        acc[mi][ni] = __builtin_amdgcn_mfma_f32_16x16x32_bf16(                 \
            af[mi][1], bfr[ni][1], acc[mi][ni], 0, 0, 0);                      \
      }                                                                        \
    __builtin_amdgcn_s_setprio(0);                                             \
  }

  // tiles 0..11: groups of 3, buffers cycle 0,1,2; stage target = tile+2
  for (int g = 0; g < 4; ++g) {
    const int kb = g * 192;
    KTILE(0, 2, kb,       true, false);
    KTILE(1, 0, kb + 64,  true, false);
    KTILE(2, 1, kb + 128, true, false);
  }
  // peeled tail: tiles 12..15
  KTILE(0, 2, 768, true,  false);  // stages tile 14
  KTILE(1, 0, 832, true,  false);  // stages tile 15
  KTILE(2, 1, 896, false, false);
  KTILE(0, 2, 960, false, true);
#undef KTILE

  // epilogue: C/D layout col = lane&15, row = (lane>>4)*4 + reg  [m89/m91]
  const int rowb = kg * 4;
#pragma unroll
  for (int ni = 0; ni < 4; ++ni) {
    const int cl = wc * 64 + ni * 16 + l15;
    const float bv_ = bias[nloc + cl];
#pragma unroll
    for (int mi = 0; mi < 4; ++mi) {
      const int row = m0 + wr * 64 + mi * 16 + rowb;
#pragma unroll
      for (int j = 0; j < 4; ++j)
        QKV[(size_t)(row + j) * 3072 + n0g + cl] = (bf16)(acc[mi][ni][j] + bv_);
    }
  }
}

// ------- local attention, window +-2; QKV fused rows [p][3072] ------------
__global__ void local_attn_kernel(const bf16* __restrict__ QKV,
                                  float* __restrict__ out) {
  const int t = threadIdx.x;
  const int lane = t & 63, wid = t >> 6;
  const int p = blockIdx.x * 4 + wid;  // b*2048 + s
  const int s = p & 2047;
  const size_t hoff = (size_t)lane * 16;

  float qf[16];
  {
    const bf16* qp = QKV + (size_t)p * 3072 + hoff;
    bf16x8 q0 = *reinterpret_cast<const bf16x8*>(qp);
    bf16x8 q1 = *reinterpret_cast<const bf16x8*>(qp + 8);
#pragma unroll
    for (int j = 0; j < 8; ++j) { qf[j] = (float)q0[j]; qf[8 + j] = (float)q1[j]; }
  }

  float sc[5];
#pragma unroll
  for (int w = 0; w < 5; ++w) {
    const int sp = s + w - 2;  // wave-uniform
    if (sp < 0 || sp >= 2048) { sc[w] = -__builtin_inff(); continue; }
    const bf16* kp = QKV + (size_t)(p + w - 2) * 3072 + 1024 + hoff;
    bf16x8 k0 = *reinterpret_cast<const bf16x8*>(kp);
    bf16x8 k1 = *reinterpret_cast<const bf16x8*>(kp + 8);
    float d = 0.f;
#pragma unroll
    for (int j = 0; j < 8; ++j) d += qf[j] * (float)k0[j] + qf[8 + j] * (float)k1[j];
#pragma unroll
    for (int off = 32; off >= 1; off >>= 1) d += __shfl_xor(d, off, 64);
    sc[w] = d * (1.0f / 32.0f);  // /sqrt(1024)
  }

  float m = -__builtin_inff();
#pragma unroll
  for (int w = 0; w < 5; ++w) m = fmaxf(m, sc[w]);
  float e[5], sum = 0.f;
#pragma unroll
  for (int w = 0; w < 5; ++w) { e[w] = __expf(sc[w] - m); sum += e[w]; }
  const float inv = 1.0f / sum;

  float of[16];
#pragma unroll
  for (int j = 0; j < 16; ++j) of[j] = 0.f;
#pragma unroll
  for (int w = 0; w < 5; ++w) {
    const int sp = s + w - 2;
    if (sp < 0 || sp >= 2048) continue;
    const float pw = e[w] * inv;
    const bf16* vp = QKV + (size_t)(p + w - 2) * 3072 + 2048 + hoff;
    bf16x8 v0 = *reinterpret_cast<const bf16x8*>(vp);
    bf16x8 v1 = *reinterpret_cast<const bf16x8*>(vp + 8);
#pragma unroll
    for (int j = 0; j < 8; ++j) { of[j] += pw * (float)v0[j]; of[8 + j] += pw * (float)v1[j]; }
  }

  float* op = out + (size_t)p * 1024 + hoff;
#pragma unroll
  for (int j4 = 0; j4 < 4; ++j4) {
    f32x4 o = {of[4 * j4 + 0], of[4 * j4 + 1], of[4 * j4 + 2], of[4 * j4 + 3]};
    *reinterpret_cast<f32x4*>(op + 4 * j4) = o;
  }
}

extern "C" void kernel_launch(void* const* d_in, const int* in_sizes, int n_in,
                              void* d_out, int out_size, void* d_ws,
                              size_t ws_size, hipStream_t stream) {
  const float* x  = (const float*)d_in[0];
  const float* Wq = (const float*)d_in[1];
  const float* bq = (const float*)d_in[2];
  const float* Wk = (const float*)d_in[3];
  const float* bk = (const float*)d_in[4];
  const float* Wv = (const float*)d_in[5];
  const float* bv = (const float*)d_in[6];

  char* ws = (char*)d_ws;
  bf16* xb  = (bf16*)ws;                       // 16 MB: x as bf16
  bf16* Wt  = (bf16*)(ws + (size_t)16777216);  // 6 MB: [3072][1024] W^T bf16
  bf16* QKV = (bf16*)(ws + (size_t)23068672);  // 48 MB: fused [8192][3072]
  float* outf = (float*)d_out;

  cast_bf16_kernel<<<8192, 256, 0, stream>>>(x, xb, 8192 * 1024 / 4);
  transpose_cast_kernel<<<dim3(32, 32, 3), 256, 0, stream>>>(Wq, Wk, Wv, Wt);
  qkv_gemm_kernel<<<dim3(24, 32), 512, 0, stream>>>(xb, Wt, bq, bk, bv, QKV);
  local_attn_kernel<<<2048, 256, 0, stream>>>(QKV, outf);
}